// Round 5
// baseline (448.627 us; speedup 1.0000x reference)
//
#include <hip/hip_runtime.h>

#define B_TOT   4096
#define T_STEPS 512
#define IN_F    5
#define D_FC    32
#define D_H     64
#define MB      4       // batches per block: every lane owns exactly 1 cell
#define NROW    16      // MFMA M-tile rows staged in LDS (batch b -> row 4b)
#define ROWPAD  104     // f16 elems per row (96 + 8 pad; rows stay 16B-aligned)

typedef _Float16 h8 __attribute__((ext_vector_type(8)));
typedef float    f4 __attribute__((ext_vector_type(4)));

#define LOG2E    1.4426950408889634f
#define TWOLOG2E 2.8853900817779268f

__device__ __forceinline__ float fexp2(float x) { return __builtin_amdgcn_exp2f(x); }
__device__ __forceinline__ float frcp(float x)  { return __builtin_amdgcn_rcpf(x); }

__global__ __launch_bounds__(256, 4) void lstm_mfma(
    const float* __restrict__ x,
    const float* __restrict__ W0,
    const float* __restrict__ b0,
    const float* __restrict__ W_ih,
    const float* __restrict__ W_hh,
    const float* __restrict__ b_ih,
    const float* __restrict__ b_hh,
    const float* __restrict__ Wo,
    const float* __restrict__ bo,
    float* __restrict__ out)
{
    // double-buffered Hcat: [k 0..31]=h0(t), [32..95]=h(t-1), f16
    __shared__ _Float16 H[2][NROW][ROWPAD];

    const int tid  = threadIdx.x;
    const int lane = tid & 63;
    const int w    = tid >> 6;      // wave id: owns hidden j in [w*16, w*16+16)
    const int col  = lane & 15;
    const int quad = lane >> 4;     // = batch index within block (row 4*quad)
    const int bblk = blockIdx.x * MB;

    // ---- resident B-fragments: lane holds gate q for j=w*16+col across K ----
    h8 Bf[4][3];
    #pragma unroll
    for (int q = 0; q < 4; ++q) {
        const int row = q * 64 + w * 16 + col;
        #pragma unroll
        for (int c = 0; c < 3; ++c) {
            h8 f;
            #pragma unroll
            for (int jj = 0; jj < 8; ++jj) {
                const int k = c * 32 + quad * 8 + jj;
                const float wv = (k < D_FC) ? W_ih[row * D_FC + k]
                                            : W_hh[row * D_H + (k - D_FC)];
                f[jj] = (_Float16)wv;
            }
            Bf[q][c] = f;
        }
    }
    // gate biases pre-scaled into the activation's exp2 argument:
    // sigmoid: exp2(-LOG2E*g + bs)  with bs = -LOG2E*bias
    // tanh(g): exp2(TWOLOG2E*g + bt) with bt = TWOLOG2E*bias
    float bs_i, bs_f, bt_g, bs_o;
    {
        const int r0 = 0 * 64 + w * 16 + col;
        const int r1 = 1 * 64 + w * 16 + col;
        const int r2 = 2 * 64 + w * 16 + col;
        const int r3 = 3 * 64 + w * 16 + col;
        bs_i = -LOG2E    * (b_ih[r0] + b_hh[r0]);
        bs_f = -LOG2E    * (b_ih[r1] + b_hh[r1]);
        bt_g =  TWOLOG2E * (b_ih[r2] + b_hh[r2]);
        bs_o = -LOG2E    * (b_ih[r3] + b_hh[r3]);
    }

    // ---- fc0: wave w handles batch w; column = lane&31 (store by lanes<32) ----
    const int fc = lane & 31;
    float w0c[IN_F], b0s;
    #pragma unroll
    for (int i = 0; i < IN_F; ++i) w0c[i] = W0[fc * IN_F + i];
    b0s = b0[fc];

    const float* xb = x + (size_t)(bblk + w) * T_STEPS * IN_F;

    // ---- zero both buffers (garbage rows + h region), then seed h0(0) ----
    for (int i = tid; i < 2 * NROW * 96; i += 256) {
        const int p  = i / (NROW * 96);
        const int rr = (i / 96) % NROW;
        const int cc = i % 96;
        H[p][rr][cc] = (_Float16)0.0f;
    }
    __syncthreads();

    {
        float a = b0s;
        #pragma unroll
        for (int i = 0; i < IN_F; ++i) a = fmaf(w0c[i], xb[i], a);
        if (lane < 32) H[0][4 * w][fc] = (_Float16)a;
    }
    // prefetch x(t=1)
    float xr[IN_F];
    #pragma unroll
    for (int i = 0; i < IN_F; ++i) xr[i] = xb[IN_F + i];

    float c_st = 0.0f;          // cell state for (batch quad, j = w*16+col)
    const f4 zero4 = {0.0f, 0.0f, 0.0f, 0.0f};   // loop-invariant C seed

    __syncthreads();

    for (int t = 0; t < T_STEPS; ++t) {
        const int rp = t & 1, wp = rp ^ 1;

        // A-fragments (b128, 16B aligned)
        const h8 A0 = *(const h8*)&H[rp][col][quad * 8];
        const h8 A1 = *(const h8*)&H[rp][col][32 + quad * 8];
        const h8 A2 = *(const h8*)&H[rp][col][64 + quad * 8];

        f4 acc[4];
        #pragma unroll
        for (int q = 0; q < 4; ++q) {
            f4 a = __builtin_amdgcn_mfma_f32_16x16x32_f16(A0, Bf[q][0], zero4, 0, 0, 0);
            a = __builtin_amdgcn_mfma_f32_16x16x32_f16(A1, Bf[q][1], a, 0, 0, 0);
            a = __builtin_amdgcn_mfma_f32_16x16x32_f16(A2, Bf[q][2], a, 0, 0, 0);
            acc[q] = a;
        }

        // elementwise LSTM, one cell per lane (reg 0 = row 4*quad = batch quad)
        {
            const float ei = fexp2(fmaf(-LOG2E,    acc[0][0], bs_i));
            const float ii = frcp(1.0f + ei);
            const float ef = fexp2(fmaf(-LOG2E,    acc[1][0], bs_f));
            const float ff = frcp(1.0f + ef);
            const float eg = fexp2(fmaf(TWOLOG2E,  acc[2][0], bt_g));
            const float g_ = fmaf(-2.0f, frcp(1.0f + eg), 1.0f);
            const float eo = fexp2(fmaf(-LOG2E,    acc[3][0], bs_o));
            const float oo = frcp(1.0f + eo);
            c_st = fmaf(ff, c_st, ii * g_);
            const float ec = fexp2(TWOLOG2E * c_st);
            const float th = fmaf(-2.0f, frcp(1.0f + ec), 1.0f);
            const float hh = oo * th;
            H[wp][4 * quad][D_FC + w * 16 + col] = (_Float16)hh;
        }

        // fc0 for t+1 (all lanes compute; lanes<32 store)
        {
            float a = b0s;
            #pragma unroll
            for (int i = 0; i < IN_F; ++i) a = fmaf(w0c[i], xr[i], a);
            if (lane < 32) H[wp][4 * w][fc] = (_Float16)a;
        }
        // prefetch x(t+2), clamped
        const int tn = (t + 2 < T_STEPS) ? (t + 2) : (T_STEPS - 1);
        #pragma unroll
        for (int i = 0; i < IN_F; ++i) xr[i] = xb[tn * IN_F + i];

        __syncthreads();   // single barrier: buf[wp] writes visible for next step
    }

    // ---- output head: h_last lives in H[0] (T even) ----
    if (tid < MB) {
        float a = bo[0];
        #pragma unroll 8
        for (int j = 0; j < D_H; ++j)
            a = fmaf((float)H[0][4 * tid][D_FC + j], Wo[j], a);
        out[bblk + tid] = a;
    }
}

extern "C" void kernel_launch(void* const* d_in, const int* in_sizes, int n_in,
                              void* d_out, int out_size, void* d_ws, size_t ws_size,
                              hipStream_t stream) {
    const float* x    = (const float*)d_in[0];
    const float* W0   = (const float*)d_in[1];
    const float* b0   = (const float*)d_in[2];
    const float* W_ih = (const float*)d_in[3];
    const float* W_hh = (const float*)d_in[4];
    const float* b_ih = (const float*)d_in[5];
    const float* b_hh = (const float*)d_in[6];
    const float* Wo   = (const float*)d_in[7];
    const float* bo   = (const float*)d_in[8];
    float* out = (float*)d_out;

    hipLaunchKernelGGL(lstm_mfma, dim3(B_TOT / MB), dim3(256), 0, stream,
                       x, W0, b0, W_ih, W_hh, b_ih, b_hh, Wo, bo, out);
}